// Round 14
// baseline (110.430 us; speedup 1.0000x reference)
//
#include <hip/hip_runtime.h>
#include <hip/hip_bf16.h>

#define B_ 2
#define N_ 2048
#define HID_ 256
#define HEADS_ 4
#define D_ 64
#define POOL_ 128
#define LOG2E_ 1.4426950408889634f

typedef __bf16 bf16;
typedef __bf16 bf16x8 __attribute__((ext_vector_type(8)));
typedef float f32x4 __attribute__((ext_vector_type(4)));

__device__ __forceinline__ float fast_tanh(float x) {
    x = fminf(fmaxf(x, -15.f), 15.f);
    float t = __expf(2.f * x);
    return (t - 1.f) / (t + 1.f);
}

// ---------------- fused setup: adjbits + input proj + weight transposes ----------------
__global__ void k_setup(const int* __restrict__ adj, unsigned* __restrict__ am,
                        const float* __restrict__ ge, const float* __restrict__ iw,
                        const float* __restrict__ ib, bf16* __restrict__ xb,
                        const float* __restrict__ proj_w, const float* __restrict__ ipw1,
                        const float* __restrict__ pw1, bf16* __restrict__ wT0,
                        bf16* __restrict__ wT1, bf16* __restrict__ ipw1T,
                        bf16* __restrict__ w1T0, bf16* __restrict__ w1T1) {
    int blk = blockIdx.x, tid = threadIdx.x;
    if (blk < 32768) {
        // adjacency -> bitmask via ballot
        int gid = blk * 256 + tid;
        int v = adj[gid];
        unsigned long long mask = __ballot(v > 0);
        int lane = tid & 63;
        if (lane == 0) am[gid >> 5] = (unsigned)mask;
        else if (lane == 32) am[gid >> 5] = (unsigned)(mask >> 32);
    } else if (blk < 36864) {
        // input projection -> bf16 only
        int row = blk - 32768;
        float g = ge[row];
        float v = fmaxf(g * iw[tid] + ib[tid], 0.f);
        xb[row * HID_ + tid] = (bf16)v;
    } else {
        // weight transposes: f32 [256][Nc] -> bf16 [Nc][256]
        int o = (blk - 36864) * 256 + tid;
        const float* src; bf16* dst; int Nc, loc;
        if (o < 65536)       { src = proj_w;         dst = wT0;   Nc = 256; loc = o; }
        else if (o < 131072) { src = proj_w + 65536; dst = wT1;   Nc = 256; loc = o - 65536; }
        else if (o < 163840) { src = ipw1;           dst = ipw1T; Nc = 128; loc = o - 131072; }
        else if (o < 196608) { src = pw1;            dst = w1T0;  Nc = 128; loc = o - 163840; }
        else                 { src = pw1 + 32768;    dst = w1T1;  Nc = 128; loc = o - 196608; }
        int n = loc >> 8, k = loc & 255;
        dst[loc] = (bf16)src[k * Nc + n];
    }
}

// ---------------- pool partial body: score GEMM + exp + weighted partial sum ----------------
__device__ __forceinline__ void pool_sw_body(const bf16* __restrict__ A,
                                             const bf16* __restrict__ W1T,
                                             const float* __restrict__ b1,
                                             const float* __restrict__ w2,
                                             const float* __restrict__ b2,
                                             float* __restrict__ part,
                                             float* __restrict__ pz,
                                             int slot, int b, int ch, char* smemraw) {
    int n0 = ch * 16;
    int tid = threadIdx.x;
    int w = tid >> 6, lane = tid & 63, r = lane & 15, g = lane >> 4;
    const bf16* ap = A + ((long long)(b * N_ + n0) + r) * 256 + g * 8;
    f32x4 acc[2] = {{0,0,0,0},{0,0,0,0}};
    for (int ks = 0; ks < 256; ks += 32) {
        bf16x8 af = *(const bf16x8*)(ap + ks);
        #pragma unroll
        for (int nf = 0; nf < 2; ++nf) {
            bf16x8 bfr = *(const bf16x8*)(W1T + (w * 32 + nf * 16 + r) * 256 + ks + g * 8);
            acc[nf] = __builtin_amdgcn_mfma_f32_16x16x32_bf16(af, bfr, acc[nf], 0, 0, 0);
        }
    }
    float b1v[2], w2v[2];
    #pragma unroll
    for (int nf = 0; nf < 2; ++nf) {
        b1v[nf] = b1[w * 32 + nf * 16 + r];
        w2v[nf] = w2[w * 32 + nf * 16 + r];
    }
    float (*pred)[16] = (float (*)[16])smemraw;          // [4][16]
    float* el = (float*)(smemraw + 256);                 // [16]
    #pragma unroll
    for (int q = 0; q < 4; ++q) {
        float p = fast_tanh(acc[0][q] + b1v[0]) * w2v[0] + fast_tanh(acc[1][q] + b1v[1]) * w2v[1];
        p += __shfl_xor(p, 1); p += __shfl_xor(p, 2);
        p += __shfl_xor(p, 4); p += __shfl_xor(p, 8);
        if (r == 0) pred[w][g * 4 + q] = p;
    }
    __syncthreads();
    if (tid < 16) {
        float s = pred[0][tid] + pred[1][tid] + pred[2][tid] + pred[3][tid] + b2[0];
        el[tid] = __expf(s);                 // |s| small: no max shift needed
    }
    __syncthreads();
    if (tid == 0) {
        float z = 0.f;
        #pragma unroll
        for (int n = 0; n < 16; ++n) z += el[n];
        pz[(slot * B_ + b) * 128 + ch] = z;
    }
    const bf16* xp = A + (long long)(b * N_ + n0) * 256 + tid;
    float accum = 0.f;
    #pragma unroll
    for (int n = 0; n < 16; ++n) accum += el[n] * (float)xp[n * 256];
    part[(((long long)slot * B_ + b) * 128 + ch) * 256 + tid] = accum;
}

// ------ merged: gemm_h (blocks 0-255) + pool partials (blocks 256-511) ------
// epilogue writes separable-exp tables: srcEE[i]=(e^s, e^{0.2s}), dstFF[j]=(e^d, e^{0.2d})
__global__ __launch_bounds__(256) void k_gemm_h_pool(const bf16* __restrict__ A,
                                                     const bf16* __restrict__ WT,
                                                     const float* __restrict__ as,
                                                     const float* __restrict__ ad,
                                                     bf16* __restrict__ hbT,
                                                     float2* __restrict__ srcEE,
                                                     float2* __restrict__ dstFF,
                                                     const bf16* __restrict__ W1T,
                                                     const float* __restrict__ b1,
                                                     const float* __restrict__ w2,
                                                     const float* __restrict__ b2,
                                                     float* __restrict__ part,
                                                     float* __restrict__ pz, int slot) {
    __shared__ __align__(16) char smem[16640];           // tr[64][65] f32 / pool scratch
    int blk = blockIdx.x;
    if (blk >= 256) {
        int pb = blk - 256;
        pool_sw_body(A, W1T, b1, w2, b2, part, pz, slot, pb >> 7, pb & 127, smem);
        return;
    }
    int i0 = (blk & 63) * 64, hd = blk >> 6;
    int n0 = hd * 64;
    int w = threadIdx.x >> 6, lane = threadIdx.x & 63, r = lane & 15, g = lane >> 4;
    const bf16* ap = A + (i0 + w * 16 + r) * 256 + g * 8;
    f32x4 acc[4] = {{0,0,0,0},{0,0,0,0},{0,0,0,0},{0,0,0,0}};
    for (int ks = 0; ks < 256; ks += 32) {
        bf16x8 af = *(const bf16x8*)(ap + ks);
        #pragma unroll
        for (int nf = 0; nf < 4; ++nf) {
            bf16x8 bfr = *(const bf16x8*)(WT + (n0 + nf * 16 + r) * 256 + ks + g * 8);
            acc[nf] = __builtin_amdgcn_mfma_f32_16x16x32_bf16(af, bfr, acc[nf], 0, 0, 0);
        }
    }
    int b = i0 >> 11, nbase = i0 & 2047;
    int bh = b * HEADS_ + hd;
    float asv[4], adv[4];
    #pragma unroll
    for (int nf = 0; nf < 4; ++nf) {
        asv[nf] = as[hd * 64 + nf * 16 + r] * LOG2E_;   // scores in exp2 domain
        adv[nf] = ad[hd * 64 + nf * 16 + r] * LOG2E_;
    }
    float (*tr)[65] = (float (*)[65])smem;
    #pragma unroll
    for (int q = 0; q < 4; ++q) {
        int ln = w * 16 + g * 4 + q;
        float ps = 0.f, pd = 0.f;
        #pragma unroll
        for (int nf = 0; nf < 4; ++nf) {
            float v = acc[nf][q];
            ps += v * asv[nf];
            pd += v * adv[nf];
            tr[nf * 16 + r][ln] = v;
        }
        ps += __shfl_xor(ps, 1); ps += __shfl_xor(ps, 2);
        ps += __shfl_xor(ps, 4); ps += __shfl_xor(ps, 8);
        pd += __shfl_xor(pd, 1); pd += __shfl_xor(pd, 2);
        pd += __shfl_xor(pd, 4); pd += __shfl_xor(pd, 8);
        if (r == 0) {
            // separable leaky-exp tables (exp2 domain, pre-scaled by log2e)
            srcEE[bh * N_ + nbase + ln] =
                make_float2(__builtin_amdgcn_exp2f(ps), __builtin_amdgcn_exp2f(0.2f * ps));
            dstFF[bh * N_ + nbase + ln] =
                make_float2(__builtin_amdgcn_exp2f(pd), __builtin_amdgcn_exp2f(0.2f * pd));
        }
    }
    __syncthreads();
    // coalesced hbT write: [bh][d][n]
    int ld = threadIdx.x >> 2, ln0 = (threadIdx.x & 3) * 16;
    bf16x8 o0, o1;
    #pragma unroll
    for (int e = 0; e < 8; ++e) {
        o0[e] = (bf16)tr[ld][ln0 + e];
        o1[e] = (bf16)tr[ld][ln0 + 8 + e];
    }
    bf16* hp = hbT + ((long long)bh * D_ + ld) * N_ + nbase + ln0;
    *(bf16x8*)(hp) = o0;
    *(bf16x8*)(hp + 8) = o1;
}

// ---------------- standalone pool partials (for the last pool) ----------------
__global__ __launch_bounds__(256) void k_pool_sw(const bf16* __restrict__ A,
                                                 const bf16* __restrict__ W1T,
                                                 const float* __restrict__ b1,
                                                 const float* __restrict__ w2,
                                                 const float* __restrict__ b2,
                                                 float* __restrict__ part,
                                                 float* __restrict__ pz, int slot) {
    __shared__ __align__(16) char smem[320];
    pool_sw_body(A, W1T, b1, w2, b2, part, pz, slot, blockIdx.y, blockIdx.x, smem);
}

// ---------------- fused GAT attention v9: v8 structure + separable exp (no transcendental) ------
// e_ij = m * ((s+d>=0) ? E_i*F_j : E'_i*F'_j); branch test via F'_j >= 1/E'_i (monotone proxy).
__global__ __launch_bounds__(1024, 8) void k_attn(const float2* __restrict__ srcEE,
                                                  const float2* __restrict__ dstFF,
                                                  const unsigned* __restrict__ am,
                                                  const bf16* __restrict__ hbT,
                                                  float* __restrict__ nodeOut,
                                                  bf16* __restrict__ xbNext) {
    int it = blockIdx.x, hd = blockIdx.y, b = blockIdx.z;
    int i0 = it * 32;
    int tid = threadIdx.x;
    int w = tid >> 6, lane = tid & 63, r = lane & 15, g = lane >> 4;
    int rg = w >> 3, wj = w & 7;          // rowgroup (2x16 rows), j-slice (8x32 j per tile)
    int bh = b * HEADS_ + hd;
    const float2* ffrow = dstFF + bh * N_;
    const bf16* vbase = hbT + (long long)bh * D_ * N_;

    // vtile [64][264] bf16 (33792 B) aliased with epilogue accs [8][16][68] f32 (34816 B)
    __shared__ __align__(16) char smem[34816];
    bf16* vt = (bf16*)smem;
    float (*accs)[16][68] = (float (*)[16][68])smem;
    __shared__ float lred[16][16];

    int i = i0 + rg * 16 + r;
    const unsigned* mrow = am + ((long long)(b * N_ + i)) * 64;
    unsigned mw[8];
    #pragma unroll
    for (int t = 0; t < 8; ++t) mw[t] = mrow[t * 8 + wj];
    float2 ee = srcEE[bh * N_ + i];
    float E = ee.x, Ep = ee.y;
    float T = __builtin_amdgcn_rcpf(Ep);     // threshold: c <=> F' >= 1/E'

    f32x4 acc[4] = {{0,0,0,0},{0,0,0,0},{0,0,0,0},{0,0,0,0}};
    float l = 0.f;

    // prefetch tile 0 into registers (each thread: 2 slots of 16B)
    bf16x8 st[2];
    #pragma unroll
    for (int k = 0; k < 2; ++k) {
        int s = tid + k * 1024, d = s >> 5, seg = s & 31;
        st[k] = *(const bf16x8*)(vbase + d * N_ + seg * 8);
    }

    #pragma unroll
    for (int t = 0; t < 8; ++t) {
        #pragma unroll
        for (int k = 0; k < 2; ++k) {
            int s = tid + k * 1024, d = s >> 5, seg = s & 31;
            *(bf16x8*)(vt + d * 264 + seg * 8) = st[k];
        }
        __syncthreads();
        if (t < 7) {
            #pragma unroll
            for (int k = 0; k < 2; ++k) {
                int s = tid + k * 1024, d = s >> 5, seg = s & 31;
                st[k] = *(const bf16x8*)(vbase + d * N_ + (t + 1) * 256 + seg * 8);
            }
        }
        // this wave's 32-j slice within the tile
        int jb = t * 256 + wj * 32 + g * 8;
        float4 q0 = *(const float4*)(ffrow + jb);
        float4 q1 = *(const float4*)(ffrow + jb + 2);
        float4 q2 = *(const float4*)(ffrow + jb + 4);
        float4 q3 = *(const float4*)(ffrow + jb + 6);
        float Fv[8]  = {q0.x, q0.z, q1.x, q1.z, q2.x, q2.z, q3.x, q3.z};
        float Fpv[8] = {q0.y, q0.w, q1.y, q1.w, q2.y, q2.w, q3.y, q3.w};
        unsigned mb = (mw[t] >> (g * 8)) & 0xFFu;
        bf16x8 af;
        float es[8];
        #pragma unroll
        for (int tt = 0; tt < 8; ++tt) {
            bool c = Fpv[tt] >= T;                       // s+d >= 0
            float e2 = (c ? E : Ep) * (c ? Fv[tt] : Fpv[tt]);
            e2 = ((mb >> tt) & 1u) ? e2 : 0.f;
            es[tt] = e2;
            af[tt] = (bf16)e2;
        }
        l += ((es[0] + es[1]) + (es[2] + es[3])) + ((es[4] + es[5]) + (es[6] + es[7]));
        #pragma unroll
        for (int nf = 0; nf < 4; ++nf) {
            bf16x8 vf = *(const bf16x8*)(vt + (nf * 16 + r) * 264 + wj * 32 + g * 8);
            acc[nf] = __builtin_amdgcn_mfma_f32_16x16x32_bf16(af, vf, acc[nf], 0, 0, 0);
        }
        __syncthreads();
    }

    // combine g-groups within wave (disjoint j)
    l += __shfl_xor(l, 16);
    l += __shfl_xor(l, 32);
    if (g == 0) lred[w][r] = l;

    // two-phase epilogue: rowgroup 0 then rowgroup 1 (accs reused, stays 34.8 KB)
    #pragma unroll
    for (int ph = 0; ph < 2; ++ph) {
        if (rg == ph) {
            #pragma unroll
            for (int nf = 0; nf < 4; ++nf)
                #pragma unroll
                for (int q = 0; q < 4; ++q)
                    accs[wj][g * 4 + q][nf * 16 + r] = acc[nf][q];
        }
        __syncthreads();
        {
            int rr = tid >> 6;          // 0..15
            int cc = tid & 63;
            float ls = 0.f, v = 0.f;
            #pragma unroll
            for (int w2 = 0; w2 < 8; ++w2) {
                ls += lred[ph * 8 + w2][rr];
                v += accs[w2][rr][cc];
            }
            v /= ls;
            float o = v > 0.f ? v : expm1f(v);   // elu
            int idx = (b * N_ + i0 + ph * 16 + rr) * HID_ + hd * D_ + cc;
            nodeOut[idx] = o;
            xbNext[idx] = (bf16)o;
        }
        __syncthreads();
    }
}

// ---------------- all pool finals in one launch: grid (slot*B + b) ----------------
__global__ __launch_bounds__(256) void k_pool_finals(const float* __restrict__ part,
                                                     const float* __restrict__ pz,
                                                     float* __restrict__ outRaw,
                                                     float* __restrict__ pool0,
                                                     float* __restrict__ pool1) {
    int slot = blockIdx.x >> 1, b = blockIdx.x & 1;
    int tid = threadIdx.x;
    int lane = tid & 63, w = tid >> 6;
    float z = (tid < 128) ? pz[(slot * B_ + b) * 128 + tid] : 0.f;
    #pragma unroll
    for (int o = 1; o < 64; o <<= 1) z += __shfl_xor(z, o);
    __shared__ float red[4];
    if (lane == 0) red[w] = z;
    __syncthreads();
    float Z = red[0] + red[1] + red[2] + red[3];
    float acc = 0.f;
    #pragma unroll 8
    for (int ch = 0; ch < 128; ++ch)
        acc += part[(((long long)slot * B_ + b) * 128 + ch) * 256 + tid];
    float* out = slot == 0 ? outRaw : (slot == 1 ? pool0 : pool1);
    out[b * HID_ + tid] = acc / Z;
}

extern "C" void kernel_launch(void* const* d_in, const int* in_sizes, int n_in,
                              void* d_out, int out_size, void* d_ws, size_t ws_size,
                              hipStream_t stream) {
    const float* ge     = (const float*)d_in[0];
    const int*   adj    = (const int*)d_in[1];
    const float* in_w   = (const float*)d_in[2];
    const float* in_b   = (const float*)d_in[3];
    const float* proj_w = (const float*)d_in[4];
    const float* a_src  = (const float*)d_in[5];
    const float* a_dst  = (const float*)d_in[6];
    const float* pw1    = (const float*)d_in[7];
    const float* pb1    = (const float*)d_in[8];
    const float* pw2    = (const float*)d_in[9];
    const float* pb2    = (const float*)d_in[10];
    const float* ipw1   = (const float*)d_in[11];
    const float* ipb1   = (const float*)d_in[12];
    const float* ipw2   = (const float*)d_in[13];
    const float* ipb2   = (const float*)d_in[14];

    char* ws = (char*)d_ws;
    bf16*     xb    = (bf16*)(ws + 0);             // 2 MB
    bf16*     hbT   = (bf16*)(ws + 2097152);       // 2 MB
    float2*   srcEE = (float2*)(ws + 4194304);     // 128 KB
    float2*   dstFF = (float2*)(ws + 4325376);     // 128 KB
    unsigned* am    = (unsigned*)(ws + 4456448);   // 1 MB
    bf16*     wT0   = (bf16*)(ws + 5505024);       // 128 KB
    bf16*     wT1   = wT0 + 65536;                 // 128 KB
    bf16*     ipw1T = wT1 + 65536;                 // 64 KB
    bf16*     w1T0  = ipw1T + 32768;               // 64 KB
    bf16*     w1T1  = w1T0 + 32768;                // 64 KB
    float*    part  = (float*)(ws + 5963776);      // 768 KB (3 slots)
    float*    pz    = (float*)(ws + 6750208);      // 3 KB

    float* outRaw = (float*)d_out;
    float* node0  = outRaw + 512;
    float* node1  = node0 + 1048576;
    float* pool0  = node1 + 1048576;
    float* pool1  = pool0 + 512;

    k_setup<<<37760, 256, 0, stream>>>(adj, am, ge, in_w, in_b, xb,
                                       proj_w, ipw1, pw1, wT0, wT1, ipw1T, w1T0, w1T1);

    // L0 gemm_h + raw pool partials (both read initial xb)
    k_gemm_h_pool<<<512, 256, 0, stream>>>(xb, wT0, a_src, a_dst, hbT, srcEE, dstFF,
                                           ipw1T, ipb1, ipw2, ipb2, part, pz, 0);
    k_attn<<<dim3(64, 4, 2), 1024, 0, stream>>>(srcEE, dstFF, am, hbT, node0, xb);

    // L1 gemm_h + pool(l0) partials (both read xb = node0 bf16)
    k_gemm_h_pool<<<512, 256, 0, stream>>>(xb, wT1, a_src + 256, a_dst + 256, hbT, srcEE, dstFF,
                                           w1T0, pb1, pw2, pb2, part, pz, 1);
    k_attn<<<dim3(64, 4, 2), 1024, 0, stream>>>(srcEE, dstFF, am, hbT, node1, xb);

    // pool(l1) partials on xb = node1 bf16
    k_pool_sw<<<dim3(128, B_), 256, 0, stream>>>(xb, w1T1, pb1 + POOL_, pw2 + 1, pb2 + 1,
                                                 part, pz, 2);
    k_pool_finals<<<6, 256, 0, stream>>>(part, pz, outRaw, pool0, pool1);
}

// Round 15
// 100.460 us; speedup vs baseline: 1.0992x; 1.0992x over previous
//
#include <hip/hip_runtime.h>
#include <hip/hip_bf16.h>

#define B_ 2
#define N_ 2048
#define HID_ 256
#define HEADS_ 4
#define D_ 64
#define POOL_ 128
#define LOG2E_ 1.4426950408889634f

typedef __bf16 bf16;
typedef __bf16 bf16x8 __attribute__((ext_vector_type(8)));
typedef float f32x4 __attribute__((ext_vector_type(4)));

__device__ __forceinline__ float fast_tanh(float x) {
    x = fminf(fmaxf(x, -15.f), 15.f);
    float t = __expf(2.f * x);
    return (t - 1.f) / (t + 1.f);
}

// ---------------- fused setup: adjbits + input proj + weight transposes ----------------
__global__ void k_setup(const int* __restrict__ adj, unsigned* __restrict__ am,
                        const float* __restrict__ ge, const float* __restrict__ iw,
                        const float* __restrict__ ib, bf16* __restrict__ xb,
                        const float* __restrict__ proj_w, const float* __restrict__ ipw1,
                        const float* __restrict__ pw1, bf16* __restrict__ wT0,
                        bf16* __restrict__ wT1, bf16* __restrict__ ipw1T,
                        bf16* __restrict__ w1T0, bf16* __restrict__ w1T1) {
    int blk = blockIdx.x, tid = threadIdx.x;
    if (blk < 32768) {
        // adjacency -> bitmask via ballot
        int gid = blk * 256 + tid;
        int v = adj[gid];
        unsigned long long mask = __ballot(v > 0);
        int lane = tid & 63;
        if (lane == 0) am[gid >> 5] = (unsigned)mask;
        else if (lane == 32) am[gid >> 5] = (unsigned)(mask >> 32);
    } else if (blk < 36864) {
        // input projection -> bf16 only
        int row = blk - 32768;
        float g = ge[row];
        float v = fmaxf(g * iw[tid] + ib[tid], 0.f);
        xb[row * HID_ + tid] = (bf16)v;
    } else {
        // weight transposes: f32 [256][Nc] -> bf16 [Nc][256]
        int o = (blk - 36864) * 256 + tid;
        const float* src; bf16* dst; int Nc, loc;
        if (o < 65536)       { src = proj_w;         dst = wT0;   Nc = 256; loc = o; }
        else if (o < 131072) { src = proj_w + 65536; dst = wT1;   Nc = 256; loc = o - 65536; }
        else if (o < 163840) { src = ipw1;           dst = ipw1T; Nc = 128; loc = o - 131072; }
        else if (o < 196608) { src = pw1;            dst = w1T0;  Nc = 128; loc = o - 163840; }
        else                 { src = pw1 + 32768;    dst = w1T1;  Nc = 128; loc = o - 196608; }
        int n = loc >> 8, k = loc & 255;
        dst[loc] = (bf16)src[k * Nc + n];
    }
}

// ---------------- pool partial body: score GEMM + exp + weighted partial sum ----------------
__device__ __forceinline__ void pool_sw_body(const bf16* __restrict__ A,
                                             const bf16* __restrict__ W1T,
                                             const float* __restrict__ b1,
                                             const float* __restrict__ w2,
                                             const float* __restrict__ b2,
                                             float* __restrict__ part,
                                             float* __restrict__ pz,
                                             int slot, int b, int ch, char* smemraw) {
    int n0 = ch * 16;
    int tid = threadIdx.x;
    int w = tid >> 6, lane = tid & 63, r = lane & 15, g = lane >> 4;
    const bf16* ap = A + ((long long)(b * N_ + n0) + r) * 256 + g * 8;
    f32x4 acc[2] = {{0,0,0,0},{0,0,0,0}};
    for (int ks = 0; ks < 256; ks += 32) {
        bf16x8 af = *(const bf16x8*)(ap + ks);
        #pragma unroll
        for (int nf = 0; nf < 2; ++nf) {
            bf16x8 bfr = *(const bf16x8*)(W1T + (w * 32 + nf * 16 + r) * 256 + ks + g * 8);
            acc[nf] = __builtin_amdgcn_mfma_f32_16x16x32_bf16(af, bfr, acc[nf], 0, 0, 0);
        }
    }
    float b1v[2], w2v[2];
    #pragma unroll
    for (int nf = 0; nf < 2; ++nf) {
        b1v[nf] = b1[w * 32 + nf * 16 + r];
        w2v[nf] = w2[w * 32 + nf * 16 + r];
    }
    float (*pred)[16] = (float (*)[16])smemraw;          // [4][16]
    float* el = (float*)(smemraw + 256);                 // [16]
    #pragma unroll
    for (int q = 0; q < 4; ++q) {
        float p = fast_tanh(acc[0][q] + b1v[0]) * w2v[0] + fast_tanh(acc[1][q] + b1v[1]) * w2v[1];
        p += __shfl_xor(p, 1); p += __shfl_xor(p, 2);
        p += __shfl_xor(p, 4); p += __shfl_xor(p, 8);
        if (r == 0) pred[w][g * 4 + q] = p;
    }
    __syncthreads();
    if (tid < 16) {
        float s = pred[0][tid] + pred[1][tid] + pred[2][tid] + pred[3][tid] + b2[0];
        el[tid] = __expf(s);                 // |s| small: no max shift needed
    }
    __syncthreads();
    if (tid == 0) {
        float z = 0.f;
        #pragma unroll
        for (int n = 0; n < 16; ++n) z += el[n];
        pz[(slot * B_ + b) * 128 + ch] = z;
    }
    const bf16* xp = A + (long long)(b * N_ + n0) * 256 + tid;
    float accum = 0.f;
    #pragma unroll
    for (int n = 0; n < 16; ++n) accum += el[n] * (float)xp[n * 256];
    part[(((long long)slot * B_ + b) * 128 + ch) * 256 + tid] = accum;
}

// ---------------- merged: gemm_h (blocks 0-255) + pool partials (blocks 256-511) ----------------
__global__ __launch_bounds__(256) void k_gemm_h_pool(const bf16* __restrict__ A,
                                                     const bf16* __restrict__ WT,
                                                     const float* __restrict__ as,
                                                     const float* __restrict__ ad,
                                                     bf16* __restrict__ hbT,
                                                     float* __restrict__ srcM,
                                                     float* __restrict__ dstT,
                                                     const bf16* __restrict__ W1T,
                                                     const float* __restrict__ b1,
                                                     const float* __restrict__ w2,
                                                     const float* __restrict__ b2,
                                                     float* __restrict__ part,
                                                     float* __restrict__ pz, int slot) {
    __shared__ __align__(16) char smem[16640];           // tr[64][65] f32 / pool scratch
    int blk = blockIdx.x;
    if (blk >= 256) {
        int pb = blk - 256;
        pool_sw_body(A, W1T, b1, w2, b2, part, pz, slot, pb >> 7, pb & 127, smem);
        return;
    }
    int i0 = (blk & 63) * 64, hd = blk >> 6;
    int n0 = hd * 64;
    int w = threadIdx.x >> 6, lane = threadIdx.x & 63, r = lane & 15, g = lane >> 4;
    const bf16* ap = A + (i0 + w * 16 + r) * 256 + g * 8;
    f32x4 acc[4] = {{0,0,0,0},{0,0,0,0},{0,0,0,0},{0,0,0,0}};
    for (int ks = 0; ks < 256; ks += 32) {
        bf16x8 af = *(const bf16x8*)(ap + ks);
        #pragma unroll
        for (int nf = 0; nf < 4; ++nf) {
            bf16x8 bfr = *(const bf16x8*)(WT + (n0 + nf * 16 + r) * 256 + ks + g * 8);
            acc[nf] = __builtin_amdgcn_mfma_f32_16x16x32_bf16(af, bfr, acc[nf], 0, 0, 0);
        }
    }
    int b = i0 >> 11, nbase = i0 & 2047;
    int bh = b * HEADS_ + hd;
    float asv[4], adv[4];
    #pragma unroll
    for (int nf = 0; nf < 4; ++nf) {
        asv[nf] = as[hd * 64 + nf * 16 + r] * LOG2E_;   // pre-scale: scores in exp2 domain
        adv[nf] = ad[hd * 64 + nf * 16 + r] * LOG2E_;
    }
    float (*tr)[65] = (float (*)[65])smem;
    #pragma unroll
    for (int q = 0; q < 4; ++q) {
        int ln = w * 16 + g * 4 + q;
        float ps = 0.f, pd = 0.f;
        #pragma unroll
        for (int nf = 0; nf < 4; ++nf) {
            float v = acc[nf][q];
            ps += v * asv[nf];
            pd += v * adv[nf];
            tr[nf * 16 + r][ln] = v;
        }
        ps += __shfl_xor(ps, 1); ps += __shfl_xor(ps, 2);
        ps += __shfl_xor(ps, 4); ps += __shfl_xor(ps, 8);
        pd += __shfl_xor(pd, 1); pd += __shfl_xor(pd, 2);
        pd += __shfl_xor(pd, 4); pd += __shfl_xor(pd, 8);
        if (r == 0) {
            srcM[bh * N_ + nbase + ln] = ps;
            dstT[bh * N_ + nbase + ln] = pd;
        }
    }
    __syncthreads();
    // coalesced hbT write: [bh][d][n]
    int ld = threadIdx.x >> 2, ln0 = (threadIdx.x & 3) * 16;
    bf16x8 o0, o1;
    #pragma unroll
    for (int e = 0; e < 8; ++e) {
        o0[e] = (bf16)tr[ld][ln0 + e];
        o1[e] = (bf16)tr[ld][ln0 + 8 + e];
    }
    bf16* hp = hbT + ((long long)bh * D_ + ld) * N_ + nbase + ln0;
    *(bf16x8*)(hp) = o0;
    *(bf16x8*)(hp + 8) = o1;
}

// ---------------- standalone pool partials (for the last pool) ----------------
__global__ __launch_bounds__(256) void k_pool_sw(const bf16* __restrict__ A,
                                                 const bf16* __restrict__ W1T,
                                                 const float* __restrict__ b1,
                                                 const float* __restrict__ w2,
                                                 const float* __restrict__ b2,
                                                 float* __restrict__ part,
                                                 float* __restrict__ pz, int slot) {
    __shared__ __align__(16) char smem[320];
    pool_sw_body(A, W1T, b1, w2, b2, part, pz, slot, blockIdx.y, blockIdx.x, smem);
}

// ---------------- fused GAT attention v10: QBLK=64, ones-MFMA row-sum, fast elu ----------------
// 1024 thr = 4 rowgroups(16 rows) x 4 j-slices(64 j/tile). LDS V-tile + reg prefetch as v8.
// l_i accumulated via extra MFMA with B=ones; rides in accs[.][.][64].
__global__ __launch_bounds__(1024, 4) void k_attn(const float* __restrict__ srcM,
                                                  const float* __restrict__ dstT,
                                                  const unsigned* __restrict__ am,
                                                  const bf16* __restrict__ hbT,
                                                  float* __restrict__ nodeOut,
                                                  bf16* __restrict__ xbNext) {
    int it = blockIdx.x, hd = blockIdx.y, b = blockIdx.z;
    int i0 = it * 64;
    int tid = threadIdx.x;
    int w = tid >> 6, lane = tid & 63, r = lane & 15, g = lane >> 4;
    int rg = w >> 2, wj = w & 3;          // rowgroup (4x16 rows), j-slice (4x64 j per tile)
    int bh = b * HEADS_ + hd;
    const float* drow = dstT + bh * N_;
    const bf16* vbase = hbT + (long long)bh * D_ * N_;

    // vtile [64][264] bf16 (33792 B) aliased with epilogue accs [4][16][68] f32 (17408 B)
    __shared__ __align__(16) char smem[34816];
    bf16* vt = (bf16*)smem;
    float (*accs)[16][68] = (float (*)[16][68])smem;

    int i = i0 + rg * 16 + r;
    const unsigned* mrow = am + ((long long)(b * N_ + i)) * 64;
    unsigned mw[8][2];
    #pragma unroll
    for (int t = 0; t < 8; ++t) {
        mw[t][0] = mrow[t * 8 + wj * 2];
        mw[t][1] = mrow[t * 8 + wj * 2 + 1];
    }
    float sv = srcM[bh * N_ + i];

    f32x4 acc[4] = {{0,0,0,0},{0,0,0,0},{0,0,0,0},{0,0,0,0}};
    f32x4 accl = {0,0,0,0};
    bf16x8 ones;
    #pragma unroll
    for (int e = 0; e < 8; ++e) ones[e] = (bf16)1.0f;

    // prefetch tile 0 into registers (each thread: 2 slots of 16B)
    bf16x8 st[2];
    #pragma unroll
    for (int k = 0; k < 2; ++k) {
        int s = tid + k * 1024, d = s >> 5, seg = s & 31;
        st[k] = *(const bf16x8*)(vbase + d * N_ + seg * 8);
    }

    #pragma unroll
    for (int t = 0; t < 8; ++t) {
        #pragma unroll
        for (int k = 0; k < 2; ++k) {
            int s = tid + k * 1024, d = s >> 5, seg = s & 31;
            *(bf16x8*)(vt + d * 264 + seg * 8) = st[k];
        }
        __syncthreads();
        if (t < 7) {
            #pragma unroll
            for (int k = 0; k < 2; ++k) {
                int s = tid + k * 1024, d = s >> 5, seg = s & 31;
                st[k] = *(const bf16x8*)(vbase + d * N_ + (t + 1) * 256 + seg * 8);
            }
        }
        // this wave's 64-j slice within the tile, as two 32-j octet groups
        #pragma unroll
        for (int oct = 0; oct < 2; ++oct) {
            int jb = wj * 64 + oct * 32 + g * 8;     // within-tile j offset
            int jg = t * 256 + jb;                   // global j
            float4 dv0 = *(const float4*)(drow + jg);
            float4 dv1 = *(const float4*)(drow + jg + 4);
            unsigned mb = (mw[t][oct] >> (g * 8)) & 0xFFu;
            float dd[8] = {dv0.x, dv0.y, dv0.z, dv0.w, dv1.x, dv1.y, dv1.z, dv1.w};
            bf16x8 af;
            #pragma unroll
            for (int tt = 0; tt < 8; ++tt) {
                float s2 = sv + dd[tt];                     // exp2 domain (pre-scaled)
                float lv = fmaxf(s2, 0.2f * s2);            // leaky_relu(0.2)
                float e2 = __builtin_amdgcn_exp2f(lv);      // bare v_exp_f32
                e2 = ((mb >> tt) & 1u) ? e2 : 0.f;
                af[tt] = (bf16)e2;
            }
            #pragma unroll
            for (int nf = 0; nf < 4; ++nf) {
                bf16x8 vf = *(const bf16x8*)(vt + (nf * 16 + r) * 264 + jb);
                acc[nf] = __builtin_amdgcn_mfma_f32_16x16x32_bf16(af, vf, acc[nf], 0, 0, 0);
            }
            accl = __builtin_amdgcn_mfma_f32_16x16x32_bf16(af, ones, accl, 0, 0, 0);
        }
        __syncthreads();
    }

    // four-phase epilogue: one rowgroup at a time; accs[4][16][68] aliases vt
    #pragma unroll
    for (int ph = 0; ph < 4; ++ph) {
        if (rg == ph) {
            #pragma unroll
            for (int nf = 0; nf < 4; ++nf)
                #pragma unroll
                for (int q = 0; q < 4; ++q)
                    accs[wj][g * 4 + q][nf * 16 + r] = acc[nf][q];
            if (r == 0) {
                #pragma unroll
                for (int q = 0; q < 4; ++q)
                    accs[wj][g * 4 + q][64] = accl[q];
            }
        }
        __syncthreads();
        {
            int rr = tid >> 6;          // 0..15
            int cc = tid & 63;
            float ls = 0.f, v = 0.f;
            #pragma unroll
            for (int w2 = 0; w2 < 4; ++w2) {
                ls += accs[w2][rr][64];
                v += accs[w2][rr][cc];
            }
            v /= ls;
            // elu via bare v_exp_f32
            float o = v > 0.f ? v : (__builtin_amdgcn_exp2f(v * LOG2E_) - 1.f);
            int idx = (b * N_ + i0 + ph * 16 + rr) * HID_ + hd * D_ + cc;
            nodeOut[idx] = o;
            xbNext[idx] = (bf16)o;
        }
        __syncthreads();
    }
}

// ---------------- all pool finals in one launch: grid (slot*B + b) ----------------
__global__ __launch_bounds__(256) void k_pool_finals(const float* __restrict__ part,
                                                     const float* __restrict__ pz,
                                                     float* __restrict__ outRaw,
                                                     float* __restrict__ pool0,
                                                     float* __restrict__ pool1) {
    int slot = blockIdx.x >> 1, b = blockIdx.x & 1;
    int tid = threadIdx.x;
    int lane = tid & 63, w = tid >> 6;
    float z = (tid < 128) ? pz[(slot * B_ + b) * 128 + tid] : 0.f;
    #pragma unroll
    for (int o = 1; o < 64; o <<= 1) z += __shfl_xor(z, o);
    __shared__ float red[4];
    if (lane == 0) red[w] = z;
    __syncthreads();
    float Z = red[0] + red[1] + red[2] + red[3];
    float acc = 0.f;
    #pragma unroll 8
    for (int ch = 0; ch < 128; ++ch)
        acc += part[(((long long)slot * B_ + b) * 128 + ch) * 256 + tid];
    float* out = slot == 0 ? outRaw : (slot == 1 ? pool0 : pool1);
    out[b * HID_ + tid] = acc / Z;
}

extern "C" void kernel_launch(void* const* d_in, const int* in_sizes, int n_in,
                              void* d_out, int out_size, void* d_ws, size_t ws_size,
                              hipStream_t stream) {
    const float* ge     = (const float*)d_in[0];
    const int*   adj    = (const int*)d_in[1];
    const float* in_w   = (const float*)d_in[2];
    const float* in_b   = (const float*)d_in[3];
    const float* proj_w = (const float*)d_in[4];
    const float* a_src  = (const float*)d_in[5];
    const float* a_dst  = (const float*)d_in[6];
    const float* pw1    = (const float*)d_in[7];
    const float* pb1    = (const float*)d_in[8];
    const float* pw2    = (const float*)d_in[9];
    const float* pb2    = (const float*)d_in[10];
    const float* ipw1   = (const float*)d_in[11];
    const float* ipb1   = (const float*)d_in[12];
    const float* ipw2   = (const float*)d_in[13];
    const float* ipb2   = (const float*)d_in[14];

    char* ws = (char*)d_ws;
    bf16*     xb    = (bf16*)(ws + 0);             // 2 MB
    bf16*     hbT   = (bf16*)(ws + 2097152);       // 2 MB
    float*    srcM  = (float*)(ws + 4194304);      // 64 KB
    float*    dstT  = (float*)(ws + 4259840);      // 64 KB
    unsigned* am    = (unsigned*)(ws + 4325376);   // 1 MB
    bf16*     wT0   = (bf16*)(ws + 5373952);       // 128 KB
    bf16*     wT1   = wT0 + 65536;                 // 128 KB
    bf16*     ipw1T = wT1 + 65536;                 // 64 KB
    bf16*     w1T0  = ipw1T + 32768;               // 64 KB
    bf16*     w1T1  = w1T0 + 32768;                // 64 KB
    float*    part  = (float*)(ws + 5832704);      // 768 KB (3 slots)
    float*    pz    = (float*)(ws + 6619136);      // 3 KB

    float* outRaw = (float*)d_out;
    float* node0  = outRaw + 512;
    float* node1  = node0 + 1048576;
    float* pool0  = node1 + 1048576;
    float* pool1  = pool0 + 512;

    k_setup<<<37760, 256, 0, stream>>>(adj, am, ge, in_w, in_b, xb,
                                       proj_w, ipw1, pw1, wT0, wT1, ipw1T, w1T0, w1T1);

    // L0 gemm_h + raw pool partials (both read initial xb)
    k_gemm_h_pool<<<512, 256, 0, stream>>>(xb, wT0, a_src, a_dst, hbT, srcM, dstT,
                                           ipw1T, ipb1, ipw2, ipb2, part, pz, 0);
    k_attn<<<dim3(32, 4, 2), 1024, 0, stream>>>(srcM, dstT, am, hbT, node0, xb);

    // L1 gemm_h + pool(l0) partials (both read xb = node0 bf16)
    k_gemm_h_pool<<<512, 256, 0, stream>>>(xb, wT1, a_src + 256, a_dst + 256, hbT, srcM, dstT,
                                           w1T0, pb1, pw2, pb2, part, pz, 1);
    k_attn<<<dim3(32, 4, 2), 1024, 0, stream>>>(srcM, dstT, am, hbT, node1, xb);

    // pool(l1) partials on xb = node1 bf16
    k_pool_sw<<<dim3(128, B_), 256, 0, stream>>>(xb, w1T1, pb1 + POOL_, pw2 + 1, pb2 + 1,
                                                 part, pz, 2);
    k_pool_finals<<<6, 256, 0, stream>>>(part, pz, outRaw, pool0, pool1);
}